// Round 12
// baseline (272.816 us; speedup 1.0000x reference)
//
#include <hip/hip_runtime.h>
#include <hip/hip_bf16.h>

// Problem constants (LegacyScan2DOperator): B=8, H=96, W=96, D=192, C=384.
#define NB 8
#define NH 96
#define NW 96
#define ND 192
#define NC 384
#define NPOS (NB*NH*NW)            // 73728 spatial positions
#define NELEM ((size_t)NPOS*NC)    // 28,311,552 proj/local elements

#define DECAY 0.6f
#define GAIN 0.4f
#define D8  1.679616e-2f           // 0.6^8
#define D16 2.8211099e-4f          // 0.6^16

typedef __attribute__((ext_vector_type(8))) short bf16x8;
typedef __attribute__((ext_vector_type(4))) float f32x4;
typedef __attribute__((ext_vector_type(4))) unsigned short us4;

__device__ inline unsigned short f2bf(float f) {
  unsigned u = __float_as_uint(f);
  u += 0x7fff + ((u >> 16) & 1);          // RNE
  return (unsigned short)(u >> 16);
}
__device__ inline float bf2f(unsigned short u) {
  return __uint_as_float((unsigned)u << 16);
}
__device__ inline void up2(unsigned u, float& lo, float& hi) {
  lo = __uint_as_float(u << 16);
  hi = __uint_as_float(u & 0xffff0000u);
}
__device__ inline unsigned pk2(float lo, float hi) {
  return (unsigned)f2bf(lo) | ((unsigned)f2bf(hi) << 16);
}

__device__ inline void gload16(const void* g, void* l) {
  __builtin_amdgcn_global_load_lds(
      (const __attribute__((address_space(1))) void*)g,
      (__attribute__((address_space(3))) void*)l, 16, 0, 0);
}

__device__ inline f32x4 ldf4(const float* p) {
  return *reinterpret_cast<const f32x4*>(p);
}
__device__ inline f32x4 ldb4(const unsigned short* p) {
  us4 v = *reinterpret_cast<const us4*>(p);
  return (f32x4){bf2f(v.x), bf2f(v.y), bf2f(v.z), bf2f(v.w)};
}
// packed bf16x4 (uint2) <-> f32x4
__device__ inline uint2 pk4(f32x4 v) {
  us4 o = {f2bf(v[0]), f2bf(v[1]), f2bf(v[2]), f2bf(v[3])};
  uint2 r; __builtin_memcpy(&r, &o, 8); return r;
}
__device__ inline f32x4 up4(uint2 p) {
  return (f32x4){__uint_as_float(p.x << 16), __uint_as_float(p.x & 0xffff0000u),
                 __uint_as_float(p.y << 16), __uint_as_float(p.y & 0xffff0000u)};
}
// pack 8 f32 -> bf16x8
__device__ inline bf16x8 pk8(f32x4 a, f32x4 b) {
  bf16x8 r;
#pragma unroll
  for (int i = 0; i < 4; ++i) {
    r[i]     = (short)f2bf(a[i]);
    r[i + 4] = (short)f2bf(b[i]);
  }
  return r;
}

// ------------- combined weight conversions (one launch) ---------------------
__global__ __launch_bounds__(256) void cvt_w_kernel(
    const float* __restrict__ Wi, const float* __restrict__ Wo,
    unsigned short* __restrict__ WtI, unsigned short* __restrict__ WtO) {
  int idx = blockIdx.x * 256 + threadIdx.x;
  if (idx < ND * NC) {
    int k = idx / NC, c = idx % NC;
    WtI[c * ND + k] = f2bf(Wi[idx]);
  } else {
    int j = idx - ND * NC;
    int k = j / ND, d = j % ND;
    WtO[d * NC + k] = f2bf(Wo[j]);
  }
}

// ---------------- MFMA GEMM: C[M][N] = A[M][K] @ Bt[N][K]^T + bias ----------
// A_F32: stage f32 A via global_load_lds with granule-XOR swizzle, cvt at read.
// ROW_REMAP: A rows are m=(b,w,h); C rows written at (b,h,w). C f32 or bf16.
template<int K, int N, int BN, bool WRITE_BF16, bool A_F32, bool ROW_REMAP>
__global__ __launch_bounds__(256) void gemm_kernel(
    const void* __restrict__ Av,
    const unsigned short* __restrict__ Bt,
    const float* __restrict__ bias,
    void* __restrict__ Cv) {
  constexpr int NF = BN / 32;
  __shared__ __align__(16) unsigned short lsA[A_F32 ? 8192 : 4096];
  __shared__ __align__(16) unsigned short lsB[4 * BN * 8];

  const int tid = threadIdx.x;
  const int lane = tid & 63;
  const int wid = tid >> 6;
  const int wm = wid >> 1, wn = wid & 1;
  const int kg = lane >> 4, r16 = lane & 15;
  const int m0 = blockIdx.x * 128;
  const int n0 = blockIdx.y * BN;

  const unsigned short* A16 = (const unsigned short*)Av;
  const float* A32 = (const float*)Av;
  const unsigned short* srcA0 = A16; const unsigned short* srcA1 = A16;
  const float* srcAf[4]; float* dstAf[4];
  const int sa0 = tid, sa1 = tid + 256;
  if constexpr (A_F32) {
    float* lsAf = (float*)lsA;
#pragma unroll
    for (int p = 0; p < 4; ++p) {
      int s = tid + p * 256;              // 1024 slots of 16B
      int row = s >> 3, g = s & 7;
      int gg = g ^ (row & 7);
      srcAf[p] = A32 + (size_t)(m0 + row) * K + gg * 4;
      dstAf[p] = lsAf + s * 4;
    }
  } else {
    srcA0 = A16 + (size_t)(m0 + (sa0 & 127)) * K + (sa0 >> 7) * 8;
    srcA1 = A16 + (size_t)(m0 + (sa1 & 127)) * K + (sa1 >> 7) * 8;
  }
  const unsigned short* srcB0 = Bt + (size_t)(n0 + (tid & (BN - 1))) * K + (tid / BN) * 8;
  const unsigned short* srcBh = Bt;
  if constexpr (BN == 128) {
    const int sb1 = tid + 256;
    srcBh = Bt + (size_t)(n0 + (sb1 & 127)) * K + (sb1 >> 7) * 8;
  }

  int aoff[4], boff[NF];
#pragma unroll
  for (int m = 0; m < 4; ++m)
    aoff[m] = (kg * 128 + wm * 64 + m * 16 + r16) * 8;
#pragma unroll
  for (int n = 0; n < NF; ++n)
    boff[n] = (kg * BN + wn * (BN / 2) + n * 16 + r16) * 8;

  f32x4 acc[4][NF];
  float bv[NF];
#pragma unroll
  for (int n = 0; n < NF; ++n) bv[n] = bias[n0 + wn * (BN / 2) + n * 16 + r16];
#pragma unroll
  for (int m = 0; m < 4; ++m)
#pragma unroll
    for (int n = 0; n < NF; ++n)
      acc[m][n] = (f32x4){bv[n], bv[n], bv[n], bv[n]};

  for (int ks = 0; ks < K / 32; ++ks) {
    const int ke = ks * 32;
    if constexpr (A_F32) {
#pragma unroll
      for (int p = 0; p < 4; ++p) gload16(srcAf[p] + ke, dstAf[p]);
    } else {
      gload16(srcA0 + ke, &lsA[sa0 * 8]);
      gload16(srcA1 + ke, &lsA[sa1 * 8]);
    }
    gload16(srcB0 + ke, &lsB[tid * 8]);
    if constexpr (BN == 128) gload16(srcBh + ke, &lsB[(tid + 256) * 8]);
    __syncthreads();
    bf16x8 af[4], bfr[NF];
    if constexpr (A_F32) {
      const float* lsAf = (const float*)lsA;
      const int r7 = r16 & 7;
#pragma unroll
      for (int m = 0; m < 4; ++m) {
        const int rowf = wm * 64 + m * 16 + r16;
        const float* rp = lsAf + rowf * 32;
        f32x4 a0 = *reinterpret_cast<const f32x4*>(rp + ((2 * kg) ^ r7) * 4);
        f32x4 a1 = *reinterpret_cast<const f32x4*>(rp + ((2 * kg + 1) ^ r7) * 4);
        af[m] = pk8(a0, a1);
      }
    } else {
#pragma unroll
      for (int m = 0; m < 4; ++m)
        af[m] = *reinterpret_cast<const bf16x8*>(&lsA[aoff[m]]);
    }
#pragma unroll
    for (int n = 0; n < NF; ++n)
      bfr[n] = *reinterpret_cast<const bf16x8*>(&lsB[boff[n]]);
#pragma unroll
    for (int m = 0; m < 4; ++m)
#pragma unroll
      for (int n = 0; n < NF; ++n)
        acc[m][n] = __builtin_amdgcn_mfma_f32_16x16x32_bf16(af[m], bfr[n], acc[m][n], 0, 0, 0);
    __syncthreads();
  }

#pragma unroll
  for (int m = 0; m < 4; ++m) {
    const int row = m0 + wm * 64 + m * 16 + kg * 4;
#pragma unroll
    for (int n = 0; n < NF; ++n) {
      const int col = n0 + wn * (BN / 2) + n * 16 + r16;
#pragma unroll
      for (int j = 0; j < 4; ++j) {
        const int r = row + j;
        size_t orow;
        if constexpr (ROW_REMAP) {
          int bb_ = r / (NW * NH);
          int rem = r - bb_ * (NW * NH);
          int w_ = rem / NH;
          int h_ = rem - w_ * NH;
          orow = (size_t)(bb_ * NH + h_) * NW + w_;
        } else {
          orow = (size_t)r;
        }
        if constexpr (WRITE_BF16)
          ((unsigned short*)Cv)[orow * N + col] = f2bf(acc[m][n][j]);
        else
          ((float*)Cv)[orow * N + col] = acc[m][n][j];
      }
    }
  }
}

// -- fused depthwise 3x3 conv + horizontal scans (aggregate exchange) --------
// block -> (b,h) via XCD-chunked map. 576 thr = (c4, wseg of 16).
// Output: interleaved lacc records: per (b,w,h), 96 x {loc4 (8B), acc4 (8B)}
// = 1536 B. One uint4 store per (w,h) per thread -> 1024 B wave runs.
__global__ __launch_bounds__(576) void dh_kernel(
    const unsigned short* __restrict__ proj, const float* __restrict__ cw,
    unsigned* __restrict__ lacc) {
  __shared__ f32x4 agf[6][96];
  __shared__ f32x4 agb[6][96];   // 18432 B
  const int tid = threadIdx.x;
  const int c4 = tid % 96;
  const int seg = tid / 96;      // wseg 0..5
  const int w0 = seg * 16;
  const int bid = blockIdx.x;
  const int bh = (bid & 7) * NH + (bid >> 3);   // XCD-chunked (768 = 8*96)
  const int h = bh % NH;
  const int b = bh / NH;

  f32x4 raw[9];
  const float* cwp = cw + (size_t)c4 * 36;
#pragma unroll
  for (int i = 0; i < 9; ++i) raw[i] = ldf4(cwp + i * 4);
  f32x4 qq[9];
#pragma unroll
  for (int tap = 0; tap < 9; ++tap)
#pragma unroll
    for (int c = 0; c < 4; ++c)
      qq[tap][c] = raw[(c * 9 + tap) >> 2][(c * 9 + tap) & 3];

  const bool hm = (h > 0), hp = (h < NH - 1);
  const unsigned short* rowm = proj + ((size_t)(bh - 1) * NW) * NC + c4 * 4;
  const unsigned short* rowc = proj + ((size_t)bh * NW) * NC + c4 * 4;
  const unsigned short* rowp = proj + ((size_t)(bh + 1) * NW) * NC + c4 * 4;
  // lacc record base for (b, w0, h); w-stride = NH*384 uints
  unsigned* lbase = lacc + ((size_t)(b * NW + w0) * NH + h) * 384 + c4 * 4;
  const size_t wstr = (size_t)NH * 384;

  const f32x4 z = {0.f, 0.f, 0.f, 0.f};
  f32x4 colL[3], colC[3], colR[3];
  if (w0 > 0) {
    colL[0] = hm ? ldb4(rowm + (size_t)(w0 - 1) * NC) : z;
    colL[1] = ldb4(rowc + (size_t)(w0 - 1) * NC);
    colL[2] = hp ? ldb4(rowp + (size_t)(w0 - 1) * NC) : z;
  } else { colL[0] = z; colL[1] = z; colL[2] = z; }
  colC[0] = hm ? ldb4(rowm + (size_t)w0 * NC) : z;
  colC[1] = ldb4(rowc + (size_t)w0 * NC);
  colC[2] = hp ? ldb4(rowp + (size_t)w0 * NC) : z;

  uint2 xr[16];
#pragma unroll
  for (int i = 0; i < 16; ++i) {
    const int w = w0 + i;
    if (w + 1 < NW) {
      colR[0] = hm ? ldb4(rowm + (size_t)(w + 1) * NC) : z;
      colR[1] = ldb4(rowc + (size_t)(w + 1) * NC);
      colR[2] = hp ? ldb4(rowp + (size_t)(w + 1) * NC) : z;
    } else { colR[0] = z; colR[1] = z; colR[2] = z; }
    f32x4 a = colL[0] * qq[0] + colC[0] * qq[1] + colR[0] * qq[2]
            + colL[1] * qq[3] + colC[1] * qq[4] + colR[1] * qq[5]
            + colL[2] * qq[6] + colC[2] * qq[7] + colR[2] * qq[8];
    xr[i] = pk4(a);
    colL[0] = colC[0]; colL[1] = colC[1]; colL[2] = colC[2];
    colC[0] = colR[0]; colC[1] = colR[1]; colC[2] = colR[2];
  }

  f32x4 Af = z, Ab = z;
#pragma unroll
  for (int i = 0; i < 16; ++i) Af = DECAY * Af + GAIN * up4(xr[i]);
#pragma unroll
  for (int i = 15; i >= 0; --i) Ab = DECAY * Ab + GAIN * up4(xr[i]);
  agf[seg][c4] = Af; agb[seg][c4] = Ab;
  __syncthreads();
  f32x4 Fin = z, Bin = z;
  if (seg >= 1) Fin = agf[seg - 1][c4];
  if (seg >= 2) Fin += D16 * agf[seg - 2][c4];
  if (seg <= 4) Bin = agb[seg + 1][c4];
  if (seg <= 3) Bin += D16 * agb[seg + 2][c4];

  uint2 bwp[16];
  f32x4 Bs = Bin;
#pragma unroll
  for (int i = 15; i >= 0; --i) {
    Bs = DECAY * Bs + GAIN * up4(xr[i]);
    bwp[i] = pk4(Bs);
  }
  f32x4 Fs = Fin;
#pragma unroll
  for (int i = 0; i < 16; ++i) {
    Fs = DECAY * Fs + GAIN * up4(xr[i]);
    uint2 ap = pk4(Fs + up4(bwp[i]));
    uint4 rec; rec.x = xr[i].x; rec.y = xr[i].y; rec.z = ap.x; rec.w = ap.y;
    *reinterpret_cast<uint4*>(lbase + (size_t)i * wstr) = rec;
  }
}

// -- vertical scans + mix + layernorm, all-register (wave = row) -------------
// block = (b,w,half of 48 rows); 384 thr = 6 waves; wave = 8-row segment;
// lane owns ch pairs {2L, 128+2L, 256+2L}. Reads interleaved lacc records:
// one uint4 per (row, group) carries the lane's loc pair + acc pair
// (even/odd lanes share a record entry; L1 merges the duplicate load).
__global__ __launch_bounds__(384) void vln_kernel(
    const unsigned* __restrict__ lacc,
    const float* __restrict__ g, const float* __restrict__ bb,
    unsigned* __restrict__ nrm_u) {
  __shared__ float AGF[8 * 384];   // [ext seg][lane*6 + k]
  __shared__ float AGB[8 * 384];
  const int tid = threadIdx.x;
  const int lane = tid & 63;
  const int seg = tid >> 6;          // 0..5
  const int bx = blockIdx.x;
  const int half = bx & 1;
  const int bw = bx >> 1;            // b*NW + w
  const int r0 = bw * NH + half * 48 + seg * 8;   // first own row (global)
  const int odd = lane & 1;

  // ---- own loads from lacc: 3 uint4 per row ----
  unsigned xr[8][3], av[8][3];
  {
    const unsigned* rec = lacc + (size_t)r0 * 384 + (lane >> 1) * 4;
#pragma unroll
    for (int i = 0; i < 8; ++i)
#pragma unroll
      for (int j = 0; j < 3; ++j) {
        uint4 q = *reinterpret_cast<const uint4*>(rec + (size_t)i * 384 + j * 128);
        xr[i][j] = odd ? q.y : q.x;
        av[i][j] = odd ? q.w : q.z;
      }
  }

  // ---- own aggregates (fwd + bwd over 8 rows, 6 f32 lanes-worth) ----
  float Af[6] = {0, 0, 0, 0, 0, 0}, Ab[6] = {0, 0, 0, 0, 0, 0};
#pragma unroll
  for (int i = 0; i < 8; ++i) {
#pragma unroll
    for (int j = 0; j < 3; ++j) {
      float lo, hi; up2(xr[i][j], lo, hi);
      Af[2 * j]     = DECAY * Af[2 * j] + GAIN * lo;
      Af[2 * j + 1] = DECAY * Af[2 * j + 1] + GAIN * hi;
    }
  }
#pragma unroll
  for (int i = 7; i >= 0; --i) {
#pragma unroll
    for (int j = 0; j < 3; ++j) {
      float lo, hi; up2(xr[i][j], lo, hi);
      Ab[2 * j]     = DECAY * Ab[2 * j] + GAIN * lo;
      Ab[2 * j + 1] = DECAY * Ab[2 * j + 1] + GAIN * hi;
    }
  }
  {
    float* fp = &AGF[(2 + seg) * 384 + lane * 6];
    float* bp = &AGB[seg * 384 + lane * 6];
#pragma unroll
    for (int k = 0; k < 6; ++k) { fp[k] = Af[k]; bp[k] = Ab[k]; }
  }

  // ---- warmup aggregates for the cross-half boundary (tid < 128) ----
  if (tid < 128) {
    const int sw = seg;                          // 0 or 1
    const int hw = half ? (32 + sw * 8) : (48 + sw * 8);
    const unsigned* wrec = lacc + ((size_t)(bw * NH + hw)) * 384 + (lane >> 1) * 4;
    unsigned wrow[8][3];
#pragma unroll
    for (int i = 0; i < 8; ++i)
#pragma unroll
      for (int j = 0; j < 3; ++j) {
        uint4 q = *reinterpret_cast<const uint4*>(wrec + (size_t)i * 384 + j * 128);
        wrow[i][j] = odd ? q.y : q.x;
      }
    float wa[6] = {0, 0, 0, 0, 0, 0};
    if (half) {                                  // fwd aggregate (rows below)
#pragma unroll
      for (int i = 0; i < 8; ++i)
#pragma unroll
        for (int j = 0; j < 3; ++j) {
          float lo, hi; up2(wrow[i][j], lo, hi);
          wa[2 * j]     = DECAY * wa[2 * j] + GAIN * lo;
          wa[2 * j + 1] = DECAY * wa[2 * j + 1] + GAIN * hi;
        }
      float* fp = &AGF[sw * 384 + lane * 6];
      float* bp = &AGB[(6 + sw) * 384 + lane * 6];
#pragma unroll
      for (int k = 0; k < 6; ++k) { fp[k] = wa[k]; bp[k] = 0.f; }
    } else {                                     // bwd aggregate (rows above)
#pragma unroll
      for (int i = 7; i >= 0; --i)
#pragma unroll
        for (int j = 0; j < 3; ++j) {
          float lo, hi; up2(wrow[i][j], lo, hi);
          wa[2 * j]     = DECAY * wa[2 * j] + GAIN * lo;
          wa[2 * j + 1] = DECAY * wa[2 * j + 1] + GAIN * hi;
        }
      float* bp = &AGB[(6 + sw) * 384 + lane * 6];
      float* fp = &AGF[sw * 384 + lane * 6];
#pragma unroll
      for (int k = 0; k < 6; ++k) { bp[k] = wa[k]; fp[k] = 0.f; }
    }
  }
  __syncthreads();

  // ---- scan-init from aggregates (3-term correction, trunc ~ 0.6^24) ----
  float Fin[6], Bin[6];
  {
    const float* f1 = &AGF[(seg + 1) * 384 + lane * 6];
    const float* f2 = &AGF[seg * 384 + lane * 6];
    const float* b1 = &AGB[(seg + 1) * 384 + lane * 6];
    const float* b2 = &AGB[(seg + 2) * 384 + lane * 6];
#pragma unroll
    for (int k = 0; k < 6; ++k) {
      Fin[k] = f1[k] + D8 * f2[k];
      Bin[k] = b1[k] + D8 * b2[k];
    }
    if (seg >= 1) {
      const float* f3 = &AGF[(seg - 1) * 384 + lane * 6];
#pragma unroll
      for (int k = 0; k < 6; ++k) Fin[k] += D16 * f3[k];
    }
    if (seg <= 4) {
      const float* b3 = &AGB[(seg + 3) * 384 + lane * 6];
#pragma unroll
      for (int k = 0; k < 6; ++k) Bin[k] += D16 * b3[k];
    }
  }

  // ---- bwd scan -> packed bt ----
  unsigned bt[8][3];
  {
    float Bs[6];
#pragma unroll
    for (int k = 0; k < 6; ++k) Bs[k] = Bin[k];
#pragma unroll
    for (int i = 7; i >= 0; --i) {
#pragma unroll
      for (int j = 0; j < 3; ++j) {
        float lo, hi; up2(xr[i][j], lo, hi);
        Bs[2 * j]     = DECAY * Bs[2 * j] + GAIN * lo;
        Bs[2 * j + 1] = DECAY * Bs[2 * j + 1] + GAIN * hi;
        bt[i][j] = pk2(Bs[2 * j], Bs[2 * j + 1]);
      }
    }
  }

  // ---- gamma/beta for this lane's channels ----
  float gv[6], bv[6];
  {
    float2 g0 = *reinterpret_cast<const float2*>(&g[2 * lane]);
    float2 g1 = *reinterpret_cast<const float2*>(&g[128 + 2 * lane]);
    float2 g2 = *reinterpret_cast<const float2*>(&g[256 + 2 * lane]);
    float2 b0 = *reinterpret_cast<const float2*>(&bb[2 * lane]);
    float2 b1 = *reinterpret_cast<const float2*>(&bb[128 + 2 * lane]);
    float2 b2 = *reinterpret_cast<const float2*>(&bb[256 + 2 * lane]);
    gv[0] = g0.x; gv[1] = g0.y; gv[2] = g1.x; gv[3] = g1.y; gv[4] = g2.x; gv[5] = g2.y;
    bv[0] = b0.x; bv[1] = b0.y; bv[2] = b1.x; bv[3] = b1.y; bv[4] = b2.x; bv[5] = b2.y;
  }

  // ---- fwd scan + mix + per-row wave LN + store ----
  float Fs[6];
#pragma unroll
  for (int k = 0; k < 6; ++k) Fs[k] = Fin[k];
  unsigned* op = nrm_u + (size_t)r0 * 192 + lane;
#pragma unroll
  for (int i = 0; i < 8; ++i) {
    float m6[6];
    float sm = 0.f, sq = 0.f;
#pragma unroll
    for (int j = 0; j < 3; ++j) {
      float xlo, xhi, alo, ahi, blo, bhi;
      up2(xr[i][j], xlo, xhi);
      up2(av[i][j], alo, ahi);
      up2(bt[i][j], blo, bhi);
      Fs[2 * j]     = DECAY * Fs[2 * j] + GAIN * xlo;
      Fs[2 * j + 1] = DECAY * Fs[2 * j + 1] + GAIN * xhi;
      float mlo = xlo + 0.25f * (alo + Fs[2 * j] + blo);
      float mhi = xhi + 0.25f * (ahi + Fs[2 * j + 1] + bhi);
      m6[2 * j] = mlo; m6[2 * j + 1] = mhi;
      sm += mlo + mhi;
      sq += mlo * mlo + mhi * mhi;
    }
#pragma unroll
    for (int o = 32; o > 0; o >>= 1) {
      sm += __shfl_xor(sm, o, 64);
      sq += __shfl_xor(sq, o, 64);
    }
    float mu = sm * (1.f / NC);
    float rr = rsqrtf(sq * (1.f / NC) - mu * mu + 1e-5f);
#pragma unroll
    for (int j = 0; j < 3; ++j) {
      float nlo = (m6[2 * j] - mu) * rr * gv[2 * j] + bv[2 * j];
      float nhi = (m6[2 * j + 1] - mu) * rr * gv[2 * j + 1] + bv[2 * j + 1];
      op[(size_t)i * 192 + j * 64] = pk2(nlo, nhi);
    }
  }
}

extern "C" void kernel_launch(void* const* d_in, const int* in_sizes, int n_in,
                              void* d_out, int out_size, void* d_ws, size_t ws_size,
                              hipStream_t stream) {
  const float* x    = (const float*)d_in[0];
  const float* W_in = (const float*)d_in[1];
  const float* b_in = (const float*)d_in[2];
  const float* cw   = (const float*)d_in[3];
  const float* ln_g = (const float*)d_in[4];
  const float* ln_b = (const float*)d_in[5];
  const float* W_out= (const float*)d_in[6];
  const float* b_out= (const float*)d_in[7];
  float* out = (float*)d_out;

  // workspace layout (~170 MB)
  unsigned short* wsu  = (unsigned short*)d_ws;
  unsigned short* proj = wsu;                          // 28,311,552 ushorts (b,h,w,c)
  unsigned* lacc       = (unsigned*)(wsu + 28311552);  // 28,311,552 uints (b,w,h)[c4]{loc,acc}
  unsigned short* WtI  = (unsigned short*)(lacc + 28311552);  // 73,728
  unsigned short* WtO  = WtI + 73728;                  // 73,728
  unsigned short* nrm_t = proj;   // aliases proj (dead after dh_kernel)

  // 1) weight conversions (one launch)
  cvt_w_kernel<<<(2 * ND * NC) / 256, 256, 0, stream>>>(W_in, W_out, WtI, WtO);
  // 2) in_proj MFMA GEMM (reads f32 x directly) -> bf16 proj  [M,K=192,N=384]
  {
    dim3 g(NPOS / 128, NC / 128);
    gemm_kernel<ND, NC, 128, true, true, false><<<g, 256, 0, stream>>>(x, WtI, b_in, proj);
  }
  // 3) fused depthwise conv + horizontal scans -> interleaved lacc records
  dh_kernel<<<NB * NH, 576, 0, stream>>>(proj, cw, lacc);
  // 4) vertical scans + mix + LN, all-register -> bf16 nrm_t
  vln_kernel<<<NB * NW * 2, 384, 0, stream>>>(lacc, ln_g, ln_b, (unsigned*)nrm_t);
  // 5) out_proj MFMA GEMM with row remap -> f32 out  [M=73728, K=384, N=192]
  {
    dim3 g(NPOS / 128, ND / 64);
    gemm_kernel<NC, ND, 64, false, false, true><<<g, 256, 0, stream>>>(nrm_t, WtO, b_out, out);
  }
}

// Round 13
// 177.036 us; speedup vs baseline: 1.5410x; 1.5410x over previous
//
#include <hip/hip_runtime.h>
#include <hip/hip_bf16.h>

// Problem constants (LegacyScan2DOperator): B=8, H=96, W=96, D=192, C=384.
#define NB 8
#define NH 96
#define NW 96
#define ND 192
#define NC 384
#define NPOS (NB*NH*NW)            // 73728 spatial positions

#define DECAY 0.6f
#define GAIN 0.4f
#define D12 2.1767823e-3f          // 0.6^12
#define D16 2.8211099e-4f          // 0.6^16
#define D24 4.7383813e-6f          // 0.6^24

typedef __attribute__((ext_vector_type(8))) short bf16x8;
typedef __attribute__((ext_vector_type(4))) float f32x4;
typedef __attribute__((ext_vector_type(4))) unsigned short us4;

__device__ inline unsigned short f2bf(float f) {
  unsigned u = __float_as_uint(f);
  u += 0x7fff + ((u >> 16) & 1);          // RNE
  return (unsigned short)(u >> 16);
}
__device__ inline float bf2f(unsigned short u) {
  return __uint_as_float((unsigned)u << 16);
}

__device__ inline void gload16(const void* g, void* l) {
  __builtin_amdgcn_global_load_lds(
      (const __attribute__((address_space(1))) void*)g,
      (__attribute__((address_space(3))) void*)l, 16, 0, 0);
}

__device__ inline f32x4 ldf4(const float* p) {
  return *reinterpret_cast<const f32x4*>(p);
}
__device__ inline f32x4 ldb4(const unsigned short* p) {
  us4 v = *reinterpret_cast<const us4*>(p);
  return (f32x4){bf2f(v.x), bf2f(v.y), bf2f(v.z), bf2f(v.w)};
}
__device__ inline void stb4(unsigned short* p, f32x4 v) {
  us4 o = {f2bf(v[0]), f2bf(v[1]), f2bf(v[2]), f2bf(v[3])};
  *reinterpret_cast<us4*>(p) = o;
}
// packed bf16x4 (uint2) <-> f32x4
__device__ inline uint2 pk4(f32x4 v) {
  us4 o = {f2bf(v[0]), f2bf(v[1]), f2bf(v[2]), f2bf(v[3])};
  uint2 r; __builtin_memcpy(&r, &o, 8); return r;
}
__device__ inline f32x4 up4(uint2 p) {
  return (f32x4){__uint_as_float(p.x << 16), __uint_as_float(p.x & 0xffff0000u),
                 __uint_as_float(p.y << 16), __uint_as_float(p.y & 0xffff0000u)};
}
// pack 8 f32 -> bf16x8
__device__ inline bf16x8 pk8(f32x4 a, f32x4 b) {
  bf16x8 r;
#pragma unroll
  for (int i = 0; i < 4; ++i) {
    r[i]     = (short)f2bf(a[i]);
    r[i + 4] = (short)f2bf(b[i]);
  }
  return r;
}
// swizzled byte offset inside the mix tile: row-major 768B rows, XOR bank fix
__device__ inline unsigned mswz(int row, int byteInRow) {
  return (unsigned)(row * 768 + (byteInRow ^ ((row & 7) << 4)));
}

// ------------- combined weight conversions (one launch) ---------------------
__global__ __launch_bounds__(256) void cvt_w_kernel(
    const float* __restrict__ Wi, const float* __restrict__ Wo,
    unsigned short* __restrict__ WtI, unsigned short* __restrict__ WtO) {
  int idx = blockIdx.x * 256 + threadIdx.x;
  if (idx < ND * NC) {
    int k = idx / NC, c = idx % NC;
    WtI[c * ND + k] = f2bf(Wi[idx]);
  } else {
    int j = idx - ND * NC;
    int k = j / ND, d = j % ND;
    WtO[d * NC + k] = f2bf(Wo[j]);
  }
}

// ---------------- MFMA GEMM (in_proj): proj = x @ W_in + b ------------------
// A is f32 in global, staged raw via global_load_lds with granule-XOR swizzle.
template<int K, int N, int BN>
__global__ __launch_bounds__(256) void gemm_kernel(
    const float* __restrict__ A32,
    const unsigned short* __restrict__ Bt,
    const float* __restrict__ bias,
    unsigned short* __restrict__ C) {
  constexpr int NF = BN / 32;
  __shared__ __align__(16) unsigned short lsA[8192];
  __shared__ __align__(16) unsigned short lsB[4 * BN * 8];

  const int tid = threadIdx.x;
  const int lane = tid & 63;
  const int wid = tid >> 6;
  const int wm = wid >> 1, wn = wid & 1;
  const int kg = lane >> 4, r16 = lane & 15;
  const int m0 = blockIdx.x * 128;
  const int n0 = blockIdx.y * BN;

  const float* srcAf[4]; float* dstAf[4];
  {
    float* lsAf = (float*)lsA;
#pragma unroll
    for (int p = 0; p < 4; ++p) {
      int s = tid + p * 256;              // 1024 slots of 16B
      int row = s >> 3, g = s & 7;
      int gg = g ^ (row & 7);
      srcAf[p] = A32 + (size_t)(m0 + row) * K + gg * 4;
      dstAf[p] = lsAf + s * 4;
    }
  }
  const unsigned short* srcB0 = Bt + (size_t)(n0 + (tid & (BN - 1))) * K + (tid / BN) * 8;
  const int sb1 = tid + 256;
  const unsigned short* srcBh = Bt + (size_t)(n0 + (sb1 & 127)) * K + (sb1 >> 7) * 8;

  int boff[NF];
#pragma unroll
  for (int n = 0; n < NF; ++n)
    boff[n] = (kg * BN + wn * (BN / 2) + n * 16 + r16) * 8;

  f32x4 acc[4][NF];
  float bv[NF];
#pragma unroll
  for (int n = 0; n < NF; ++n) bv[n] = bias[n0 + wn * (BN / 2) + n * 16 + r16];
#pragma unroll
  for (int m = 0; m < 4; ++m)
#pragma unroll
    for (int n = 0; n < NF; ++n)
      acc[m][n] = (f32x4){bv[n], bv[n], bv[n], bv[n]};

  for (int ks = 0; ks < K / 32; ++ks) {
    const int ke = ks * 32;
#pragma unroll
    for (int p = 0; p < 4; ++p) gload16(srcAf[p] + ke, dstAf[p]);
    gload16(srcB0 + ke, &lsB[tid * 8]);
    if constexpr (BN == 128) gload16(srcBh + ke, &lsB[(tid + 256) * 8]);
    __syncthreads();
    bf16x8 af[4], bfr[NF];
    {
      const float* lsAf = (const float*)lsA;
      const int r7 = r16 & 7;
#pragma unroll
      for (int m = 0; m < 4; ++m) {
        const int rowf = wm * 64 + m * 16 + r16;
        const float* rp = lsAf + rowf * 32;
        f32x4 a0 = *reinterpret_cast<const f32x4*>(rp + ((2 * kg) ^ r7) * 4);
        f32x4 a1 = *reinterpret_cast<const f32x4*>(rp + ((2 * kg + 1) ^ r7) * 4);
        af[m] = pk8(a0, a1);
      }
    }
#pragma unroll
    for (int n = 0; n < NF; ++n)
      bfr[n] = *reinterpret_cast<const bf16x8*>(&lsB[boff[n]]);
#pragma unroll
    for (int m = 0; m < 4; ++m)
#pragma unroll
      for (int n = 0; n < NF; ++n)
        acc[m][n] = __builtin_amdgcn_mfma_f32_16x16x32_bf16(af[m], bfr[n], acc[m][n], 0, 0, 0);
    __syncthreads();
  }

#pragma unroll
  for (int m = 0; m < 4; ++m) {
    const int row = m0 + wm * 64 + m * 16 + kg * 4;
#pragma unroll
    for (int n = 0; n < NF; ++n) {
      const int col = n0 + wn * (BN / 2) + n * 16 + r16;
#pragma unroll
      for (int j = 0; j < 4; ++j)
        C[(size_t)(row + j) * N + col] = f2bf(acc[m][n][j]);
    }
  }
}

// -- fused depthwise 3x3 conv + horizontal scans (aggregate exchange) --------
// block -> (b,h) via XCD-chunked map: all h of one batch image on one XCD,
// so the bh-1/bh+1 proj rows are L2-resident. 576 thr = (c4, wseg of 16).
// Writes loc_t and acc_t in TRANSPOSED (b,w,h,c) layout (separate buffers —
// interleaving them regressed 2.5x via partial-line write thrash, R11).
__global__ __launch_bounds__(576) void dh_kernel(
    const unsigned short* __restrict__ proj, const float* __restrict__ cw,
    unsigned short* __restrict__ loc_t, unsigned short* __restrict__ acc_t) {
  __shared__ f32x4 agf[6][96];
  __shared__ f32x4 agb[6][96];   // 18432 B
  const int tid = threadIdx.x;
  const int c4 = tid % 96;
  const int seg = tid / 96;      // wseg 0..5
  const int w0 = seg * 16;
  const int bid = blockIdx.x;
  const int bh = (bid & 7) * NH + (bid >> 3);   // XCD-chunked (768 = 8*96)
  const int h = bh % NH;
  const int b = bh / NH;

  f32x4 raw[9];
  const float* cwp = cw + (size_t)c4 * 36;
#pragma unroll
  for (int i = 0; i < 9; ++i) raw[i] = ldf4(cwp + i * 4);
  f32x4 qq[9];
#pragma unroll
  for (int tap = 0; tap < 9; ++tap)
#pragma unroll
    for (int c = 0; c < 4; ++c)
      qq[tap][c] = raw[(c * 9 + tap) >> 2][(c * 9 + tap) & 3];

  const bool hm = (h > 0), hp = (h < NH - 1);
  const unsigned short* rowm = proj + ((size_t)(bh - 1) * NW) * NC + c4 * 4;
  const unsigned short* rowc = proj + ((size_t)bh * NW) * NC + c4 * 4;
  const unsigned short* rowp = proj + ((size_t)(bh + 1) * NW) * NC + c4 * 4;
  unsigned short* tbase = loc_t + ((size_t)(b * NW + w0) * NH + h) * NC + c4 * 4;
  unsigned short* abase = acc_t + ((size_t)(b * NW + w0) * NH + h) * NC + c4 * 4;
  const size_t wst = (size_t)NH * NC;

  const f32x4 z = {0.f, 0.f, 0.f, 0.f};
  f32x4 colL[3], colC[3], colR[3];
  if (w0 > 0) {
    colL[0] = hm ? ldb4(rowm + (size_t)(w0 - 1) * NC) : z;
    colL[1] = ldb4(rowc + (size_t)(w0 - 1) * NC);
    colL[2] = hp ? ldb4(rowp + (size_t)(w0 - 1) * NC) : z;
  } else { colL[0] = z; colL[1] = z; colL[2] = z; }
  colC[0] = hm ? ldb4(rowm + (size_t)w0 * NC) : z;
  colC[1] = ldb4(rowc + (size_t)w0 * NC);
  colC[2] = hp ? ldb4(rowp + (size_t)w0 * NC) : z;

  uint2 xr[16];
#pragma unroll
  for (int i = 0; i < 16; ++i) {
    const int w = w0 + i;
    if (w + 1 < NW) {
      colR[0] = hm ? ldb4(rowm + (size_t)(w + 1) * NC) : z;
      colR[1] = ldb4(rowc + (size_t)(w + 1) * NC);
      colR[2] = hp ? ldb4(rowp + (size_t)(w + 1) * NC) : z;
    } else { colR[0] = z; colR[1] = z; colR[2] = z; }
    f32x4 a = colL[0] * qq[0] + colC[0] * qq[1] + colR[0] * qq[2]
            + colL[1] * qq[3] + colC[1] * qq[4] + colR[1] * qq[5]
            + colL[2] * qq[6] + colC[2] * qq[7] + colR[2] * qq[8];
    xr[i] = pk4(a);
    *reinterpret_cast<uint2*>(tbase + (size_t)i * wst) = xr[i];
    colL[0] = colC[0]; colL[1] = colC[1]; colL[2] = colC[2];
    colC[0] = colR[0]; colC[1] = colR[1]; colC[2] = colR[2];
  }

  f32x4 Af = z, Ab = z;
#pragma unroll
  for (int i = 0; i < 16; ++i) Af = DECAY * Af + GAIN * up4(xr[i]);
#pragma unroll
  for (int i = 15; i >= 0; --i) Ab = DECAY * Ab + GAIN * up4(xr[i]);
  agf[seg][c4] = Af; agb[seg][c4] = Ab;
  __syncthreads();
  f32x4 Fin = z, Bin = z;
  if (seg >= 1) Fin = agf[seg - 1][c4];
  if (seg >= 2) Fin += D16 * agf[seg - 2][c4];
  if (seg <= 4) Bin = agb[seg + 1][c4];
  if (seg <= 3) Bin += D16 * agb[seg + 2][c4];

  uint2 bwp[16];
  f32x4 Bs = Bin;
#pragma unroll
  for (int i = 15; i >= 0; --i) {
    Bs = DECAY * Bs + GAIN * up4(xr[i]);
    bwp[i] = pk4(Bs);
  }
  f32x4 Fs = Fin;
#pragma unroll
  for (int i = 0; i < 16; ++i) {
    Fs = DECAY * Fs + GAIN * up4(xr[i]);
    stb4(abase + (size_t)i * wst, Fs + up4(bwp[i]));
  }
}

// -- MEGA-FUSED: vertical scans + mix + layernorm + out_proj GEMM ------------
// block = (b,w) = one 96-row M-tile; 768 threads = 12 waves (R8 had 9 — the
// extra waves are the point: 1 block/CU is forced by the 73.7KB mix tile, so
// waves/CU is the only occupancy lever). Scan: 8 segs x 12 rows, 3-term
// aggregate exchange. GEMM: 12 waves as 3x4, mix tile is the A-operand.
__global__ __launch_bounds__(768) void vgemm_kernel(
    const unsigned short* __restrict__ loc_t, const unsigned short* __restrict__ acc_t,
    const float* __restrict__ g, const float* __restrict__ bb,
    const unsigned short* __restrict__ WtO, const float* __restrict__ bo,
    float* __restrict__ out) {
  __shared__ __align__(16) unsigned short mix[96 * NC];   // 73728 B
  __shared__ __align__(16) unsigned short lsB[2][6144];   // 2 x 12288 B
  f32x4* ag = (f32x4*)mix;            // [2][8][96] multiplexed head (24.6 KB)
  char* mixc = (char*)mix;
  const int tid = threadIdx.x;
  const int lane = tid & 63;
  const int kg = lane >> 4, r16 = lane & 15;
  const int c4 = tid % 96;
  const int seg = tid / 96;                               // hseg 0..7
  const int h0 = seg * 12;
  const int bw = blockIdx.x;                              // b*NW + w

  // ---- prefetch B k-chunk 0 (async; drained by the phase-1 barrier) ----
  {
    int d = tid % 192, kgg = tid / 192;
    gload16(WtO + (size_t)d * NC + kgg * 8, &lsB[0][tid * 8]);
  }

  // ---- phase 1: vertical scans (aggregate exchange, 12-row segments) ----
  const size_t base = ((size_t)bw * NH + h0) * NC + c4 * 4;
  const unsigned short* lp = loc_t + base;
  const unsigned short* ap = acc_t + base;
  uint2 xr[12], avp[12];
#pragma unroll
  for (int i = 0; i < 12; ++i) xr[i] = *reinterpret_cast<const uint2*>(lp + (size_t)i * NC);
#pragma unroll
  for (int i = 0; i < 12; ++i) avp[i] = *reinterpret_cast<const uint2*>(ap + (size_t)i * NC);

  const f32x4 z = {0.f, 0.f, 0.f, 0.f};
  f32x4 Af = z, Ab = z;
#pragma unroll
  for (int i = 0; i < 12; ++i) Af = DECAY * Af + GAIN * up4(xr[i]);
#pragma unroll
  for (int i = 11; i >= 0; --i) Ab = DECAY * Ab + GAIN * up4(xr[i]);
  ag[seg * 96 + c4] = Af;
  ag[768 + seg * 96 + c4] = Ab;
  __syncthreads();
  f32x4 Fin = z, Bin = z;
  if (seg >= 1) Fin = ag[(seg - 1) * 96 + c4];
  if (seg >= 2) Fin += D12 * ag[(seg - 2) * 96 + c4];
  if (seg >= 3) Fin += D24 * ag[(seg - 3) * 96 + c4];
  if (seg <= 6) Bin = ag[768 + (seg + 1) * 96 + c4];
  if (seg <= 5) Bin += D12 * ag[768 + (seg + 2) * 96 + c4];
  if (seg <= 4) Bin += D24 * ag[768 + (seg + 3) * 96 + c4];
  __syncthreads();                       // aggregate area free; mix writable

  // bwd pass: partial = x + 0.25*(acc + bt) -> swizzled mix tile
  f32x4 Bs = Bin;
#pragma unroll
  for (int i = 11; i >= 0; --i) {
    f32x4 xv = up4(xr[i]);
    Bs = DECAY * Bs + GAIN * xv;
    f32x4 part = xv + 0.25f * (up4(avp[i]) + Bs);
    stb4((unsigned short*)(mixc + mswz(h0 + i, c4 * 8)), part);
  }
  // fwd pass: final = partial + 0.25*tb (own slots)
  f32x4 Fs = Fin;
#pragma unroll
  for (int i = 0; i < 12; ++i) {
    Fs = DECAY * Fs + GAIN * up4(xr[i]);
    unsigned short* slot = (unsigned short*)(mixc + mswz(h0 + i, c4 * 8));
    stb4(slot, ldb4(slot) + 0.25f * Fs);
  }
  __syncthreads();

  // ---- phase 2: layernorm in-place in LDS (12 waves, wave-per-row) ----
  const int wave = tid >> 6;
  const int cb = lane * 6;
  {
    float gv[6], bv6[6];
#pragma unroll
    for (int i = 0; i < 6; ++i) { gv[i] = g[cb + i]; bv6[i] = bb[cb + i]; }
    for (int h = wave; h < NH; h += 12) {
      ushort2* p0 = (ushort2*)(mixc + mswz(h, lane * 12));
      ushort2* p1 = (ushort2*)(mixc + mswz(h, lane * 12 + 4));
      ushort2* p2 = (ushort2*)(mixc + mswz(h, lane * 12 + 8));
      ushort2 a2 = *p0, b2 = *p1, c2 = *p2;
      float v[6];
      v[0] = bf2f(a2.x); v[1] = bf2f(a2.y);
      v[2] = bf2f(b2.x); v[3] = bf2f(b2.y);
      v[4] = bf2f(c2.x); v[5] = bf2f(c2.y);
      float sm = 0.f, s2 = 0.f;
#pragma unroll
      for (int i = 0; i < 6; ++i) { sm += v[i]; s2 += v[i] * v[i]; }
#pragma unroll
      for (int o = 32; o > 0; o >>= 1) {
        sm += __shfl_xor(sm, o, 64);
        s2 += __shfl_xor(s2, o, 64);
      }
      float mu = sm * (1.f / NC);
      float r = rsqrtf(s2 * (1.f / NC) - mu * mu + 1e-5f);
      unsigned short o6[6];
#pragma unroll
      for (int i = 0; i < 6; ++i)
        o6[i] = f2bf((v[i] - mu) * r * gv[i] + bv6[i]);
      *p0 = (ushort2){o6[0], o6[1]};
      *p1 = (ushort2){o6[2], o6[3]};
      *p2 = (ushort2){o6[4], o6[5]};
    }
  }
  __syncthreads();

  // ---- phase 3: GEMM  out[96 x 192] = mix[96 x 384] @ WtO^T + b_out ----
  const int wm = wave >> 2, wn = wave & 3;     // 3x4 waves, 32x48 tiles
  f32x4 acc[2][3];
  {
    float bv[3];
#pragma unroll
    for (int n = 0; n < 3; ++n) bv[n] = bo[wn * 48 + n * 16 + r16];
#pragma unroll
    for (int m = 0; m < 2; ++m)
#pragma unroll
      for (int n = 0; n < 3; ++n)
        acc[m][n] = (f32x4){bv[n], bv[n], bv[n], bv[n]};
  }
  for (int ks = 0; ks < 12; ++ks) {
    if (ks < 11) {
      int d = tid % 192, kgg = tid / 192;
      gload16(WtO + (size_t)d * NC + (ks + 1) * 32 + kgg * 8, &lsB[(ks + 1) & 1][tid * 8]);
    }
    const unsigned short* bufp = lsB[ks & 1];
    bf16x8 af[2], bfr[3];
#pragma unroll
    for (int m = 0; m < 2; ++m) {
      const int row = wm * 32 + m * 16 + r16;
      af[m] = *reinterpret_cast<const bf16x8*>(mixc + mswz(row, ks * 64 + kg * 16));
    }
#pragma unroll
    for (int n = 0; n < 3; ++n)
      bfr[n] = *reinterpret_cast<const bf16x8*>(&bufp[(kg * 192 + wn * 48 + n * 16 + r16) * 8]);
#pragma unroll
    for (int m = 0; m < 2; ++m)
#pragma unroll
      for (int n = 0; n < 3; ++n)
        acc[m][n] = __builtin_amdgcn_mfma_f32_16x16x32_bf16(af[m], bfr[n], acc[m][n], 0, 0, 0);
    __syncthreads();
  }

  // C write: rows are h of this (b,w) column -> out[(b,h,w)][d], f32
  const int bq = bw / NW, wq = bw % NW;
#pragma unroll
  for (int m = 0; m < 2; ++m) {
    const int hbase = wm * 32 + m * 16 + kg * 4;
#pragma unroll
    for (int n = 0; n < 3; ++n) {
      const int d = wn * 48 + n * 16 + r16;
#pragma unroll
      for (int j = 0; j < 4; ++j)
        out[((size_t)(bq * NH + hbase + j) * NW + wq) * ND + d] = acc[m][n][j];
    }
  }
}

extern "C" void kernel_launch(void* const* d_in, const int* in_sizes, int n_in,
                              void* d_out, int out_size, void* d_ws, size_t ws_size,
                              hipStream_t stream) {
  const float* x    = (const float*)d_in[0];
  const float* W_in = (const float*)d_in[1];
  const float* b_in = (const float*)d_in[2];
  const float* cw   = (const float*)d_in[3];
  const float* ln_g = (const float*)d_in[4];
  const float* ln_b = (const float*)d_in[5];
  const float* W_out= (const float*)d_in[6];
  const float* b_out= (const float*)d_in[7];
  float* out = (float*)d_out;

  // bf16 workspace layout (ushort element offsets); ~170 MB
  unsigned short* wsu   = (unsigned short*)d_ws;
  unsigned short* proj  = wsu;                          // 28,311,552 (b,h,w,c)
  unsigned short* loc_t = proj + 28311552;              // 28,311,552 (b,w,h,c)
  unsigned short* acc_t = loc_t + 28311552;             // 28,311,552 (b,w,h,c)
  unsigned short* WtI   = acc_t + 28311552;             // 73,728
  unsigned short* WtO   = WtI + 73728;                  // 73,728

  // 1) weight conversions (one launch)
  cvt_w_kernel<<<(2 * ND * NC) / 256, 256, 0, stream>>>(W_in, W_out, WtI, WtO);
  // 2) in_proj MFMA GEMM (reads f32 x directly) -> bf16 proj  [M,K=192,N=384]
  {
    dim3 g(NPOS / 128, NC / 128);
    gemm_kernel<ND, NC, 128><<<g, 256, 0, stream>>>(x, WtI, b_in, proj);
  }
  // 3) fused depthwise conv + horizontal scans -> loc_t, acc_t (transposed,
  //    XCD-chunked block map)
  dh_kernel<<<NB * NH, 576, 0, stream>>>(proj, cw, loc_t, acc_t);
  // 4) mega-fused vertical scans + mix + LN + out_proj GEMM -> f32 out
  vgemm_kernel<<<NB * NW, 768, 0, stream>>>(loc_t, acc_t, ln_g, ln_b,
                                            WtO, b_out, out);
}